// Round 8
// baseline (199.552 us; speedup 1.0000x reference)
//
#include <hip/hip_runtime.h>
#include <math.h>

// ============================================================================
// DAttention_v2 forward. Round 8: fusion round.
// Shapes: B=8, C=128, H=W=64, HK=WK=32, NS=1024, L=2048, NH=4, DH=32.
// Changes vs round 7 (passing, 183.5 us):
//   - k_stage1: kt_pack (y->f32 chanlast, x->bf16 chanlast) + k_qsum fat-merged
//     (block-range split). 768 blocks.
//   - k_wmod: 512 threads, every 128-iter loop split 4-way + LDS reduce.
//   - k_dlg: dwconv + LN + GELU + offset + grids + bilinear gather fused;
//     one output row per block (grid 8x32); t0/posg buffers eliminated.
//   - 10 launches -> 7.
// ============================================================================

#define SCALE_F 0.17677669529663687f  // 32^-0.5

typedef __attribute__((ext_vector_type(8))) short short8v;     // 8 bf16 (4 VGPR)
typedef __attribute__((ext_vector_type(8))) unsigned short u16x8;
typedef __attribute__((ext_vector_type(4))) unsigned short u16x4;
typedef __attribute__((ext_vector_type(4))) float f32x4;

static __device__ __forceinline__ unsigned short f2bf(float f) {
  unsigned int u = __builtin_bit_cast(unsigned int, f);
  u += 0x7fffu + ((u >> 16) & 1u);   // RNE (finite inputs only)
  return (unsigned short)(u >> 16);
}
static __device__ __forceinline__ float bf2f(unsigned short s) {
  unsigned int u = ((unsigned int)s) << 16;
  return __builtin_bit_cast(float, u);
}

// ---------- 1. fat stage-1: y/x transposes + masked q_ column sums ---------
// bid<256: y -> y_t (channel-last f32); 256..511: x -> xTb (channel-last bf16);
// 512..767: qsum chunk (b = idx>>5, ch = idx&31; 2 half-chunks of 32 rows).
__global__ __launch_bounds__(256) void k_stage1(
    const float* __restrict__ y, const float* __restrict__ x,
    const float* __restrict__ q_, const float* __restrict__ mask_,
    float* __restrict__ y_t, unsigned short* __restrict__ xTb,
    float* __restrict__ qpart, float* __restrict__ mpart) {
  __shared__ __align__(16) float tile[128][65];
  int bid = blockIdx.x;
  int t = threadIdx.x;
  if (bid < 256) {
    int n = bid >> 6, yy = bid & 63;
    for (int p = 0; p < 32; ++p) {
      int idx = p * 256 + t;
      int c = idx >> 6, xx = idx & 63;
      tile[c][xx] = y[((n * 128 + c) * 64 + yy) * 64 + xx];
    }
    __syncthreads();
    for (int p = 0; p < 32; ++p) {
      int idx = p * 256 + t;
      int xx = idx >> 7, c = idx & 127;
      y_t[((n * 64 + yy) * 64 + xx) * 128 + c] = tile[c][xx];
    }
  } else if (bid < 512) {
    int nb = bid - 256;
    int n = nb >> 6, yy = nb & 63;
    for (int p = 0; p < 32; ++p) {
      int idx = p * 256 + t;
      int c = idx >> 6, xx = idx & 63;
      tile[c][xx] = x[((n * 128 + c) * 64 + yy) * 64 + xx];
    }
    __syncthreads();
    for (int p = 0; p < 4; ++p) {
      int idx = p * 256 + t;
      int xx = idx >> 4, g = idx & 15;
      u16x8 v;
#pragma unroll
      for (int j = 0; j < 8; ++j) v[j] = f2bf(tile[g * 8 + j][xx]);
      *reinterpret_cast<u16x8*>(
          xTb + ((size_t)n * 4096 + yy * 64 + xx) * 128 + g * 8) = v;
    }
  } else {
    int idx = bid - 512;           // 0..255
    int b = idx >> 5, ch = idx & 31;
    int c = t & 127, hh = t >> 7;  // 2 half-chunks of 32 rows
    float acc = 0.f, ma = 0.f;
    for (int mm = 0; mm < 32; ++mm) {
      int m = ch * 64 + hh * 32 + mm;
      float mk = mask_[b * 2048 + m];
      acc += q_[(b * 2048 + m) * 128 + c] * mk;
      ma += mk;
    }
    qpart[(b * 64 + ch * 2 + hh) * 128 + c] = acc;
    if (c == 0) mpart[b * 64 + ch * 2 + hh] = ma;
  }
}

// ---------- 2. q_cond @ Wq^T, modulated+normalized wmod (512 thr) ----------
__global__ __launch_bounds__(512) void k_wmod(
    const float* __restrict__ qpart, const float* __restrict__ mpart,
    const float* __restrict__ Wq, const float* __restrict__ bq,
    const float* __restrict__ Wmd, unsigned short* __restrict__ wmodb) {
  int b = blockIdx.x;
  int t = threadIdx.x;
  int c = t & 127, qq = t >> 7;  // 0..3
  __shared__ float qc[128], q2[128], red[4][128];

  float s = 0.f;
  for (int ch = qq; ch < 64; ch += 4) s += qpart[(b * 64 + ch) * 128 + c];
  red[qq][c] = s;
  __syncthreads();
  if (t < 128) {
    float ms = 0.f;
    for (int ch = 0; ch < 64; ++ch) ms += mpart[b * 64 + ch];
    qc[c] = (red[0][c] + red[1][c] + red[2][c] + red[3][c]) / (ms + 1e-6f);
  }
  __syncthreads();
  float a = 0.f;
  for (int i = qq * 32; i < qq * 32 + 32; ++i) a += qc[i] * Wq[c * 128 + i];
  red[qq][c] = a;
  __syncthreads();
  if (t < 128)
    q2[c] = red[0][c] + red[1][c] + red[2][c] + red[3][c] + bq[c] + 1.0f;
  __syncthreads();
  float nr = 0.f;
  for (int i = qq * 32; i < qq * 32 + 32; ++i) {
    float wv = Wmd[c * 128 + i] * q2[i];
    nr += wv * wv;
  }
  red[qq][c] = nr;
  __syncthreads();
  float rs = rsqrtf(red[0][c] + red[1][c] + red[2][c] + red[3][c] + 1e-8f);
  for (int i = qq * 32; i < qq * 32 + 32; ++i)
    wmodb[(b * 128 + c) * 128 + i] = f2bf(Wmd[c * 128 + i] * q2[i] * rs);
}

// ---------- 3. q_t = wmod @ x  (bf16 MFMA GEMM, bf16 out) ------------------
__global__ __launch_bounds__(256) void k_qt_mfma(
    const unsigned short* __restrict__ wmodb,
    const unsigned short* __restrict__ xTb,
    unsigned short* __restrict__ q_tb) {
  int b = blockIdx.x;
  int n0 = blockIdx.y * 128;
  int t = threadIdx.x;
  int w = t >> 6, l = t & 63;
  int lr = l & 15, lg = l >> 4;

  __shared__ __align__(16) unsigned short Asw[128 * 128];
  __shared__ __align__(16) unsigned short Bsw[128 * 128];
  char* Ab = reinterpret_cast<char*>(Asw);
  char* Bb = reinterpret_cast<char*>(Bsw);

  const unsigned short* asrc = wmodb + (size_t)b * 128 * 128;
  const unsigned short* bsrc = xTb + ((size_t)(b & 3) * 4096 + n0) * 128;
#pragma unroll
  for (int it = 0; it < 8; ++it) {
    int idx = it * 256 + t;
    int row = idx >> 4, cb = (idx & 15) * 16;
    int dst = row * 256 + (cb ^ ((row & 7) << 4));
    *reinterpret_cast<u16x8*>(Ab + dst) = *reinterpret_cast<const u16x8*>(asrc + idx * 8);
    *reinterpret_cast<u16x8*>(Bb + dst) = *reinterpret_cast<const u16x8*>(bsrc + idx * 8);
  }
  __syncthreads();

  const f32x4 z4 = {0.f, 0.f, 0.f, 0.f};
  f32x4 acc[8][2];
#pragma unroll
  for (int mf = 0; mf < 8; ++mf) { acc[mf][0] = z4; acc[mf][1] = z4; }

#pragma unroll
  for (int ks = 0; ks < 4; ++ks) {
    int cb = ks * 64 + lg * 16;
    short8v bf[2];
#pragma unroll
    for (int nf = 0; nf < 2; ++nf) {
      int row = w * 32 + nf * 16 + lr;
      bf[nf] = *reinterpret_cast<const short8v*>(Bb + row * 256 + (cb ^ ((row & 7) << 4)));
    }
#pragma unroll
    for (int mf = 0; mf < 8; ++mf) {
      int row = mf * 16 + lr;
      short8v af = *reinterpret_cast<const short8v*>(Ab + row * 256 + (cb ^ ((row & 7) << 4)));
      acc[mf][0] = __builtin_amdgcn_mfma_f32_16x16x32_bf16(af, bf[0], acc[mf][0], 0, 0, 0);
      acc[mf][1] = __builtin_amdgcn_mfma_f32_16x16x32_bf16(af, bf[1], acc[mf][1], 0, 0, 0);
    }
  }

#pragma unroll
  for (int mf = 0; mf < 8; ++mf)
#pragma unroll
    for (int nf = 0; nf < 2; ++nf)
#pragma unroll
      for (int r = 0; r < 4; ++r) {
        int o = mf * 16 + lg * 4 + r;
        int px = n0 + w * 32 + nf * 16 + lr;
        q_tb[((size_t)(b * 128 + o)) * 4096 + px] = f2bf(acc[mf][nf][r]);
      }
}

// ---------- 4. fused dwconv + LN + GELU + offset + grids + gsample ---------
// grid (8 b, 32 output rows). Block 256. One output row (32 px) per block.
__global__ __launch_bounds__(256) void k_dlg(
    const unsigned short* __restrict__ q_tb, const float* __restrict__ dw_w,
    const float* __restrict__ dw_b, const float* __restrict__ ln_g,
    const float* __restrict__ ln_b, const float* __restrict__ off_w,
    const float* __restrict__ y_t, unsigned short* __restrict__ xsb,
    float* __restrict__ grid_out, float* __restrict__ ref_out) {
  int b = blockIdx.x, i = blockIdx.y;  // output row 0..31
  int t = threadIdx.x;
  __shared__ float tile[128][33];            // 16.9 KB (t values)
  __shared__ float red0[8][32], red1[8][32]; // 2 KB
  __shared__ float psx[32], psy[32];

  // --- depthwise 3x3 stride-2 conv: 128 c x 32 j
  for (int p = 0; p < 16; ++p) {
    int idx = p * 256 + t;
    int c = idx >> 5, j = idx & 31;
    const unsigned short* src = q_tb + (size_t)(b * 128 + c) * 4096;
    float acc = dw_b[c];
#pragma unroll
    for (int dy = 0; dy < 3; ++dy) {
      int yy = 2 * i - 1 + dy;
      if (yy < 0 || yy > 63) continue;
#pragma unroll
      for (int dx = 0; dx < 3; ++dx) {
        int xx = 2 * j - 1 + dx;
        if (xx < 0 || xx > 63) continue;
        acc += dw_w[c * 9 + dy * 3 + dx] * bf2f(src[yy * 64 + xx]);
      }
    }
    tile[c][j] = acc;
  }
  __syncthreads();

  // --- LN partial sums: 8 groups of 16 channels
  int j = t & 31, cg = t >> 5;
  float sum = 0.f, sq = 0.f;
  for (int cc = 0; cc < 16; ++cc) {
    float v = tile[cg * 16 + cc][j];
    sum += v; sq += v * v;
  }
  red0[cg][j] = sum; red1[cg][j] = sq;
  __syncthreads();
  float tsum = 0.f, tsq = 0.f;
#pragma unroll
  for (int g = 0; g < 8; ++g) { tsum += red0[g][j]; tsq += red1[g][j]; }
  float mu = tsum * (1.0f / 128.0f);
  float var = tsq * (1.0f / 128.0f) - mu * mu;
  float rstd = 1.0f / sqrtf(var + 1e-5f);
  float o0 = 0.f, o1 = 0.f;
  for (int cc = 0; cc < 16; ++cc) {
    int c = cg * 16 + cc;
    float xn = (tile[c][j] - mu) * rstd * ln_g[c] + ln_b[c];
    float g = 0.5f * xn * (1.0f + erff(xn * 0.7071067811865476f));
    o0 += off_w[c] * g;
    o1 += off_w[128 + c] * g;
  }
  __syncthreads();
  red0[cg][j] = o0; red1[cg][j] = o1;
  __syncthreads();
  if (t < 32) {
    float off0 = 0.f, off1 = 0.f;
#pragma unroll
    for (int g = 0; g < 8; ++g) { off0 += red0[g][t]; off1 += red1[g][t]; }
    float offy = tanhf(off0) * (1.0f / 31.0f) * 2.0f;
    float offx = tanhf(off1) * (1.0f / 31.0f) * 2.0f;
    float ry = (0.5f + (float)i) / 31.0f * 2.0f - 1.0f;
    float rx = (0.5f + (float)t) / 31.0f * 2.0f - 1.0f;
    float posy = offy + ry;
    float posx = offx + rx;
    int sg = i * 32 + t;
    int bp = (b & 3) * 2 + (b >> 2);
    float2 g2; g2.x = posx; g2.y = posy;
    *reinterpret_cast<float2*>(&grid_out[(bp * 1024 + sg) * 2]) = g2;
    float2 r2; r2.x = ry; r2.y = rx;
    *reinterpret_cast<float2*>(&ref_out[(b * 1024 + sg) * 2]) = r2;
    psx[t] = (posx + 1.0f) * 0.5f * 63.0f;
    psy[t] = (posy + 1.0f) * 0.5f * 63.0f;
  }
  __syncthreads();

  // --- bilinear gather (zero-pad border): 32 px x 128 c
  int n = b & 3;
  for (int p = 0; p < 16; ++p) {
    int idx = p * 256 + t;
    int c = idx & 127, px = idx >> 7;  // 0..31
    float gx = psx[px], gy = psy[px];
    float x0 = floorf(gx), y0 = floorf(gy);
    float x1 = x0 + 1.0f, y1 = y0 + 1.0f;
    float wa = (x1 - gx) * (y1 - gy);
    float wb = (gx - x0) * (y1 - gy);
    float wc = (x1 - gx) * (gy - y0);
    float wd = (gx - x0) * (gy - y0);
    const float* base = y_t + n * 64 * 64 * 128 + c;
    float acc = 0.f;
    if (x0 >= 0.f && x0 <= 63.f && y0 >= 0.f && y0 <= 63.f)
      acc += wa * base[((int)y0 * 64 + (int)x0) * 128];
    if (x1 >= 0.f && x1 <= 63.f && y0 >= 0.f && y0 <= 63.f)
      acc += wb * base[((int)y0 * 64 + (int)x1) * 128];
    if (x0 >= 0.f && x0 <= 63.f && y1 >= 0.f && y1 <= 63.f)
      acc += wc * base[((int)y1 * 64 + (int)x0) * 128];
    if (x1 >= 0.f && x1 <= 63.f && y1 >= 0.f && y1 <= 63.f)
      acc += wd * base[((int)y1 * 64 + (int)x1) * 128];
    xsb[((size_t)b * 1024 + i * 32 + px) * 128 + c] = f2bf(acc);
  }
}

// ---------- 5. K / V projections via MFMA (weights cast in staging) --------
__global__ __launch_bounds__(256) void k_projkv_mfma(
    const unsigned short* __restrict__ xsb, const float* __restrict__ Wk,
    const float* __restrict__ Wv, const float* __restrict__ bk,
    const float* __restrict__ bv, unsigned short* __restrict__ kb,
    unsigned short* __restrict__ vb) {
  int b = blockIdx.x, nt = blockIdx.y, z = blockIdx.z;
  int t = threadIdx.x;
  int w = t >> 6, l = t & 63;
  int lr = l & 15, lg = l >> 4;

  __shared__ __align__(16) unsigned short Asw[128 * 128];
  __shared__ __align__(16) unsigned short Bsw[128 * 128];
  char* Ab = reinterpret_cast<char*>(Asw);
  char* Bb = reinterpret_cast<char*>(Bsw);

  const float* asrcf = (z == 0) ? Wk : Wv;
  const unsigned short* bsrc = xsb + ((size_t)b * 1024 + nt * 128) * 128;
  const float* bias = (z == 0) ? bk : bv;
#pragma unroll
  for (int it = 0; it < 8; ++it) {
    int idx = it * 256 + t;
    int row = idx >> 4, cb = (idx & 15) * 16;
    int dst = row * 256 + (cb ^ ((row & 7) << 4));
    float4 f0 = *reinterpret_cast<const float4*>(asrcf + idx * 8);
    float4 f1 = *reinterpret_cast<const float4*>(asrcf + idx * 8 + 4);
    u16x8 av;
    av[0] = f2bf(f0.x); av[1] = f2bf(f0.y); av[2] = f2bf(f0.z); av[3] = f2bf(f0.w);
    av[4] = f2bf(f1.x); av[5] = f2bf(f1.y); av[6] = f2bf(f1.z); av[7] = f2bf(f1.w);
    *reinterpret_cast<u16x8*>(Ab + dst) = av;
    *reinterpret_cast<u16x8*>(Bb + dst) = *reinterpret_cast<const u16x8*>(bsrc + idx * 8);
  }
  __syncthreads();

  const f32x4 z4 = {0.f, 0.f, 0.f, 0.f};
  f32x4 acc[8][2];
#pragma unroll
  for (int mf = 0; mf < 8; ++mf) { acc[mf][0] = z4; acc[mf][1] = z4; }

#pragma unroll
  for (int ks = 0; ks < 4; ++ks) {
    int cb = ks * 64 + lg * 16;
    short8v bf[2];
#pragma unroll
    for (int nf = 0; nf < 2; ++nf) {
      int row = w * 32 + nf * 16 + lr;
      bf[nf] = *reinterpret_cast<const short8v*>(Bb + row * 256 + (cb ^ ((row & 7) << 4)));
    }
#pragma unroll
    for (int mf = 0; mf < 8; ++mf) {
      int row = mf * 16 + lr;
      short8v af = *reinterpret_cast<const short8v*>(Ab + row * 256 + (cb ^ ((row & 7) << 4)));
      acc[mf][0] = __builtin_amdgcn_mfma_f32_16x16x32_bf16(af, bf[0], acc[mf][0], 0, 0, 0);
      acc[mf][1] = __builtin_amdgcn_mfma_f32_16x16x32_bf16(af, bf[1], acc[mf][1], 0, 0, 0);
    }
  }

  if (z == 0) {
#pragma unroll
    for (int mf = 0; mf < 8; ++mf) {
      int o0 = mf * 16 + lg * 4;
      int h = o0 >> 5, d0 = o0 & 31;
#pragma unroll
      for (int nf = 0; nf < 2; ++nf) {
        int n = nt * 128 + w * 32 + nf * 16 + lr;
        u16x4 pk;
#pragma unroll
        for (int r = 0; r < 4; ++r) pk[r] = f2bf(acc[mf][nf][r] + bias[o0 + r]);
        *reinterpret_cast<u16x4*>(kb + ((size_t)(b * 4 + h) * 1024 + n) * 32 + d0) = pk;
      }
    }
  } else {
#pragma unroll
    for (int mf = 0; mf < 8; ++mf)
#pragma unroll
      for (int nf = 0; nf < 2; ++nf)
#pragma unroll
        for (int r = 0; r < 4; ++r) {
          int o = mf * 16 + lg * 4 + r;
          int n = nt * 128 + w * 32 + nf * 16 + lr;
          vb[(size_t)(b * 128 + o) * 1024 + n] = f2bf(acc[mf][nf][r] + bias[o]);
        }
  }
}

// ---------- 6. attention: dbuf K/V, 1 barrier/tile, swizzled P -------------
__global__ __launch_bounds__(256) void k_attn_mfma(
    const float* __restrict__ q_, const unsigned short* __restrict__ kb,
    const unsigned short* __restrict__ vb, unsigned short* __restrict__ obmcb) {
  int bh = blockIdx.x;          // 32
  int b = bh >> 2, h = bh & 3;
  int m0 = blockIdx.y * 128;    // 16 tiles
  int t = threadIdx.x;
  int w = t >> 6, l = t & 63;
  int lr = l & 15, lg = l >> 4;

  __shared__ __align__(16) unsigned short K_lds[2][2048];
  __shared__ __align__(16) unsigned short V_lds[2][2048];
  __shared__ __align__(16) unsigned short P_lds[8192];

  short8v qa[2];
#pragma unroll
  for (int mf = 0; mf < 2; ++mf) {
    int m = m0 + w * 32 + mf * 16 + lr;
    const float* qp = q_ + ((size_t)(b * 2048 + m)) * 128 + h * 32 + lg * 8;
    float4 x0 = *reinterpret_cast<const float4*>(qp);
    float4 x1 = *reinterpret_cast<const float4*>(qp + 4);
    float vals[8] = {x0.x, x0.y, x0.z, x0.w, x1.x, x1.y, x1.z, x1.w};
    short8v q8;
#pragma unroll
    for (int j = 0; j < 8; ++j) q8[j] = (short)f2bf(vals[j] * SCALE_F);
    qa[mf] = q8;
  }

  const unsigned short* kbase = kb + (size_t)bh * 1024 * 32;
  const unsigned short* vbase = vb + (size_t)bh * 32 * 1024;
  int ksl_n = t & 63, ksl_d = t >> 6;
  int vsl_d = t & 31, vsl_nb = t >> 5;

  u16x8 kreg = *reinterpret_cast<const u16x8*>(kbase + ((size_t)ksl_n) * 32 + ksl_d * 8);
  u16x8 vreg = *reinterpret_cast<const u16x8*>(vbase + (size_t)vsl_d * 1024 + vsl_nb * 8);
  *reinterpret_cast<u16x8*>(&K_lds[0][t * 8]) = kreg;
  *reinterpret_cast<u16x8*>(&V_lds[0][t * 8]) = vreg;
  __syncthreads();

  const f32x4 z4 = {0.f, 0.f, 0.f, 0.f};
  f32x4 oacc[2][2];
  float lsum[2][4];
#pragma unroll
  for (int mf = 0; mf < 2; ++mf) {
#pragma unroll
    for (int df = 0; df < 2; ++df) oacc[mf][df] = z4;
#pragma unroll
    for (int r = 0; r < 4; ++r) lsum[mf][r] = 0.f;
  }

  int swzW = ((lr >> 3) & 1) << 3;
  int swzR = (lg & 1) << 3;
  int cur = 0;
  for (int nt = 0; nt < 16; ++nt) {
    if (nt < 15) {
      kreg = *reinterpret_cast<const u16x8*>(
          kbase + ((size_t)((nt + 1) * 64 + ksl_n)) * 32 + ksl_d * 8);
      vreg = *reinterpret_cast<const u16x8*>(
          vbase + (size_t)vsl_d * 1024 + (nt + 1) * 64 + vsl_nb * 8);
    }

    short8v kfr[4];
#pragma unroll
    for (int nf = 0; nf < 4; ++nf)
      kfr[nf] = *reinterpret_cast<const short8v*>(&K_lds[cur][(lg * 64 + nf * 16 + lr) * 8]);
    f32x4 s[2][4];
#pragma unroll
    for (int mf = 0; mf < 2; ++mf)
#pragma unroll
      for (int nf = 0; nf < 4; ++nf)
        s[mf][nf] = __builtin_amdgcn_mfma_f32_16x16x32_bf16(qa[mf], kfr[nf], z4, 0, 0, 0);

#pragma unroll
    for (int mf = 0; mf < 2; ++mf) {
#pragma unroll
      for (int nf = 0; nf < 4; ++nf) {
        int sbase = (w * 256 + (nf * 2 + (lr >> 3)) * 32 + mf * 16 + lg * 4) * 8 + (lr & 7);
#pragma unroll
        for (int r = 0; r < 4; ++r) {
          float pe = __expf(s[mf][nf][r]);
          lsum[mf][r] += pe;
          P_lds[(sbase + r * 8) ^ swzW] = f2bf(pe);
        }
      }
    }

#pragma unroll
    for (int ks = 0; ks < 2; ++ks) {
      short8v pa[2], vf[2];
#pragma unroll
      for (int mf = 0; mf < 2; ++mf)
        pa[mf] = *reinterpret_cast<const short8v*>(
            &P_lds[((w * 256 + (ks * 4 + lg) * 32 + mf * 16 + lr) * 8) ^ swzR]);
#pragma unroll
      for (int df = 0; df < 2; ++df)
        vf[df] = *reinterpret_cast<const short8v*>(
            &V_lds[cur][((ks * 4 + lg) * 32 + df * 16 + lr) * 8]);
#pragma unroll
      for (int mf = 0; mf < 2; ++mf)
#pragma unroll
        for (int df = 0; df < 2; ++df)
          oacc[mf][df] = __builtin_amdgcn_mfma_f32_16x16x32_bf16(pa[mf], vf[df], oacc[mf][df], 0, 0, 0);
    }

    if (nt < 15) {
      *reinterpret_cast<u16x8*>(&K_lds[cur ^ 1][t * 8]) = kreg;
      *reinterpret_cast<u16x8*>(&V_lds[cur ^ 1][t * 8]) = vreg;
      __syncthreads();
      cur ^= 1;
    }
  }

#pragma unroll
  for (int mf = 0; mf < 2; ++mf) {
#pragma unroll
    for (int r = 0; r < 4; ++r) {
      float v = lsum[mf][r];
      v += __shfl_xor(v, 1); v += __shfl_xor(v, 2);
      v += __shfl_xor(v, 4); v += __shfl_xor(v, 8);
      float inv = 1.0f / v;
      int m = m0 + w * 32 + mf * 16 + lg * 4 + r;
      unsigned short* op = obmcb + ((size_t)(b * 2048 + m)) * 128 + h * 32;
      op[lr] = f2bf(oacc[mf][0][r] * inv);
      op[16 + lr] = f2bf(oacc[mf][1][r] * inv);
    }
  }
}

// ---------- 7. output projection via MFMA ----------------------------------
__global__ __launch_bounds__(256) void k_out_mfma(
    const unsigned short* __restrict__ obmcb, const float* __restrict__ Wo,
    const float* __restrict__ bo, float* __restrict__ yo) {
  int b = blockIdx.x, mt = blockIdx.y;
  int t = threadIdx.x;
  int w = t >> 6, l = t & 63;
  int lr = l & 15, lg = l >> 4;

  __shared__ __align__(16) unsigned short Asw[128 * 128];
  __shared__ __align__(16) unsigned short Bsw[128 * 128];
  char* Ab = reinterpret_cast<char*>(Asw);
  char* Bb = reinterpret_cast<char*>(Bsw);

  const unsigned short* bsrc = obmcb + ((size_t)b * 2048 + mt * 128) * 128;
#pragma unroll
  for (int it = 0; it < 8; ++it) {
    int idx = it * 256 + t;
    int row = idx >> 4, cb = (idx & 15) * 16;
    int dst = row * 256 + (cb ^ ((row & 7) << 4));
    float4 f0 = *reinterpret_cast<const float4*>(Wo + idx * 8);
    float4 f1 = *reinterpret_cast<const float4*>(Wo + idx * 8 + 4);
    u16x8 av;
    av[0] = f2bf(f0.x); av[1] = f2bf(f0.y); av[2] = f2bf(f0.z); av[3] = f2bf(f0.w);
    av[4] = f2bf(f1.x); av[5] = f2bf(f1.y); av[6] = f2bf(f1.z); av[7] = f2bf(f1.w);
    *reinterpret_cast<u16x8*>(Ab + dst) = av;
    *reinterpret_cast<u16x8*>(Bb + dst) = *reinterpret_cast<const u16x8*>(bsrc + idx * 8);
  }
  __syncthreads();

  const f32x4 z4 = {0.f, 0.f, 0.f, 0.f};
  f32x4 acc[8][2];
#pragma unroll
  for (int mf = 0; mf < 8; ++mf) { acc[mf][0] = z4; acc[mf][1] = z4; }

#pragma unroll
  for (int ks = 0; ks < 4; ++ks) {
    int cb = ks * 64 + lg * 16;
    short8v bf[2];
#pragma unroll
    for (int nf = 0; nf < 2; ++nf) {
      int row = w * 32 + nf * 16 + lr;
      bf[nf] = *reinterpret_cast<const short8v*>(Bb + row * 256 + (cb ^ ((row & 7) << 4)));
    }
#pragma unroll
    for (int mf = 0; mf < 8; ++mf) {
      int row = mf * 16 + lr;
      short8v af = *reinterpret_cast<const short8v*>(Ab + row * 256 + (cb ^ ((row & 7) << 4)));
      acc[mf][0] = __builtin_amdgcn_mfma_f32_16x16x32_bf16(af, bf[0], acc[mf][0], 0, 0, 0);
      acc[mf][1] = __builtin_amdgcn_mfma_f32_16x16x32_bf16(af, bf[1], acc[mf][1], 0, 0, 0);
    }
  }

#pragma unroll
  for (int mf = 0; mf < 8; ++mf) {
    int o0 = mf * 16 + lg * 4;
#pragma unroll
    for (int nf = 0; nf < 2; ++nf) {
      int m = mt * 128 + w * 32 + nf * 16 + lr;
      float4 rv;
      rv.x = acc[mf][nf][0] + bo[o0 + 0];
      rv.y = acc[mf][nf][1] + bo[o0 + 1];
      rv.z = acc[mf][nf][2] + bo[o0 + 2];
      rv.w = acc[mf][nf][3] + bo[o0 + 3];
      *reinterpret_cast<float4*>(&yo[((size_t)(b * 2048 + m)) * 128 + o0]) = rv;
    }
  }
}

// ============================================================================
extern "C" void kernel_launch(void* const* d_in, const int* in_sizes, int n_in,
                              void* d_out, int out_size, void* d_ws, size_t ws_size,
                              hipStream_t stream) {
  const float* x     = (const float*)d_in[0];
  const float* y     = (const float*)d_in[1];
  const float* q_    = (const float*)d_in[2];
  const float* mask_ = (const float*)d_in[3];
  const float* Wq    = (const float*)d_in[4];
  const float* bq    = (const float*)d_in[5];
  const float* Wmd   = (const float*)d_in[6];
  const float* dw_w  = (const float*)d_in[7];
  const float* dw_b  = (const float*)d_in[8];
  const float* ln_g  = (const float*)d_in[9];
  const float* ln_b  = (const float*)d_in[10];
  const float* off_w = (const float*)d_in[11];
  const float* Wk    = (const float*)d_in[12];
  const float* bk    = (const float*)d_in[13];
  const float* Wv    = (const float*)d_in[14];
  const float* bv    = (const float*)d_in[15];
  const float* Wo    = (const float*)d_in[16];
  const float* bo    = (const float*)d_in[17];

  float* out = (float*)d_out;
  float* yo       = out;            // 8*2048*128
  float* grid_out = out + 2097152;  // 16384
  float* ref_out  = grid_out + 16384;

  float* ws    = (float*)d_ws;
  float* y_t   = ws;                // 2097152 f32
  float* qpart = y_t + 2097152;     // 65536 f32 (8*64*128)
  float* mpart = qpart + 65536;     // 512 f32
  unsigned short* kbb   = (unsigned short*)(mpart + 512);   // 1048576 u16
  unsigned short* vbb   = kbb + 1048576;                    // 1048576 u16
  unsigned short* xTb   = vbb + 1048576;                    // 2097152 u16
  unsigned short* wmodb = xTb + 2097152;                    // 131072 u16
  unsigned short* xsb   = wmodb + 131072;                   // 1048576 u16
  unsigned short* obmcb = xsb + 1048576;                    // 2097152 u16
  unsigned short* q_tb  = obmcb + 2097152;                  // 4194304 u16

  hipLaunchKernelGGL(k_stage1, dim3(768), dim3(256), 0, stream,
                     y, x, q_, mask_, y_t, xTb, qpart, mpart);
  hipLaunchKernelGGL(k_wmod, dim3(8), dim3(512), 0, stream,
                     qpart, mpart, Wq, bq, Wmd, wmodb);
  hipLaunchKernelGGL(k_qt_mfma, dim3(8, 32), dim3(256), 0, stream, wmodb, xTb, q_tb);
  hipLaunchKernelGGL(k_dlg, dim3(8, 32), dim3(256), 0, stream,
                     q_tb, dw_w, dw_b, ln_g, ln_b, off_w, y_t, xsb, grid_out, ref_out);
  hipLaunchKernelGGL(k_projkv_mfma, dim3(8, 8, 2), dim3(256), 0, stream,
                     xsb, Wk, Wv, bk, bv, kbb, vbb);
  hipLaunchKernelGGL(k_attn_mfma, dim3(32, 16), dim3(256), 0, stream, q_, kbb, vbb, obmcb);
  hipLaunchKernelGGL(k_out_mfma, dim3(8, 16), dim3(256), 0, stream, obmcb, Wo, bo, yo);
}

// Round 9
// 180.131 us; speedup vs baseline: 1.1078x; 1.1078x over previous
//
#include <hip/hip_runtime.h>
#include <math.h>

// ============================================================================
// DAttention_v2 forward. Round 9: revert k_dlg (TLP-killing fusion), keep
// k_stage1 + k_wmod(512). dwconv/ln_off/gsample back to round-7 wide grids.
// Shapes: B=8, C=128, H=W=64, HK=WK=32, NS=1024, L=2048, NH=4, DH=32.
// ============================================================================

#define SCALE_F 0.17677669529663687f  // 32^-0.5

typedef __attribute__((ext_vector_type(8))) short short8v;     // 8 bf16 (4 VGPR)
typedef __attribute__((ext_vector_type(8))) unsigned short u16x8;
typedef __attribute__((ext_vector_type(4))) unsigned short u16x4;
typedef __attribute__((ext_vector_type(4))) float f32x4;

static __device__ __forceinline__ unsigned short f2bf(float f) {
  unsigned int u = __builtin_bit_cast(unsigned int, f);
  u += 0x7fffu + ((u >> 16) & 1u);   // RNE (finite inputs only)
  return (unsigned short)(u >> 16);
}
static __device__ __forceinline__ float bf2f(unsigned short s) {
  unsigned int u = ((unsigned int)s) << 16;
  return __builtin_bit_cast(float, u);
}

// ---------- 1. fat stage-1: y/x transposes + masked q_ column sums ---------
__global__ __launch_bounds__(256) void k_stage1(
    const float* __restrict__ y, const float* __restrict__ x,
    const float* __restrict__ q_, const float* __restrict__ mask_,
    float* __restrict__ y_t, unsigned short* __restrict__ xTb,
    float* __restrict__ qpart, float* __restrict__ mpart) {
  __shared__ __align__(16) float tile[128][65];
  int bid = blockIdx.x;
  int t = threadIdx.x;
  if (bid < 256) {
    int n = bid >> 6, yy = bid & 63;
    for (int p = 0; p < 32; ++p) {
      int idx = p * 256 + t;
      int c = idx >> 6, xx = idx & 63;
      tile[c][xx] = y[((n * 128 + c) * 64 + yy) * 64 + xx];
    }
    __syncthreads();
    for (int p = 0; p < 32; ++p) {
      int idx = p * 256 + t;
      int xx = idx >> 7, c = idx & 127;
      y_t[((n * 64 + yy) * 64 + xx) * 128 + c] = tile[c][xx];
    }
  } else if (bid < 512) {
    int nb = bid - 256;
    int n = nb >> 6, yy = nb & 63;
    for (int p = 0; p < 32; ++p) {
      int idx = p * 256 + t;
      int c = idx >> 6, xx = idx & 63;
      tile[c][xx] = x[((n * 128 + c) * 64 + yy) * 64 + xx];
    }
    __syncthreads();
    for (int p = 0; p < 4; ++p) {
      int idx = p * 256 + t;
      int xx = idx >> 4, g = idx & 15;
      u16x8 v;
#pragma unroll
      for (int j = 0; j < 8; ++j) v[j] = f2bf(tile[g * 8 + j][xx]);
      *reinterpret_cast<u16x8*>(
          xTb + ((size_t)n * 4096 + yy * 64 + xx) * 128 + g * 8) = v;
    }
  } else {
    int idx = bid - 512;           // 0..255
    int b = idx >> 5, ch = idx & 31;
    int c = t & 127, hh = t >> 7;  // 2 half-chunks of 32 rows
    float acc = 0.f, ma = 0.f;
    for (int mm = 0; mm < 32; ++mm) {
      int m = ch * 64 + hh * 32 + mm;
      float mk = mask_[b * 2048 + m];
      acc += q_[(b * 2048 + m) * 128 + c] * mk;
      ma += mk;
    }
    qpart[(b * 64 + ch * 2 + hh) * 128 + c] = acc;
    if (c == 0) mpart[b * 64 + ch * 2 + hh] = ma;
  }
}

// ---------- 2. q_cond @ Wq^T, modulated+normalized wmod (512 thr) ----------
__global__ __launch_bounds__(512) void k_wmod(
    const float* __restrict__ qpart, const float* __restrict__ mpart,
    const float* __restrict__ Wq, const float* __restrict__ bq,
    const float* __restrict__ Wmd, unsigned short* __restrict__ wmodb) {
  int b = blockIdx.x;
  int t = threadIdx.x;
  int c = t & 127, qq = t >> 7;  // 0..3
  __shared__ float qc[128], q2[128], red[4][128];

  float s = 0.f;
  for (int ch = qq; ch < 64; ch += 4) s += qpart[(b * 64 + ch) * 128 + c];
  red[qq][c] = s;
  __syncthreads();
  if (t < 128) {
    float ms = 0.f;
    for (int ch = 0; ch < 64; ++ch) ms += mpart[b * 64 + ch];
    qc[c] = (red[0][c] + red[1][c] + red[2][c] + red[3][c]) / (ms + 1e-6f);
  }
  __syncthreads();
  float a = 0.f;
  for (int i = qq * 32; i < qq * 32 + 32; ++i) a += qc[i] * Wq[c * 128 + i];
  red[qq][c] = a;
  __syncthreads();
  if (t < 128)
    q2[c] = red[0][c] + red[1][c] + red[2][c] + red[3][c] + bq[c] + 1.0f;
  __syncthreads();
  float nr = 0.f;
  for (int i = qq * 32; i < qq * 32 + 32; ++i) {
    float wv = Wmd[c * 128 + i] * q2[i];
    nr += wv * wv;
  }
  red[qq][c] = nr;
  __syncthreads();
  float rs = rsqrtf(red[0][c] + red[1][c] + red[2][c] + red[3][c] + 1e-8f);
  for (int i = qq * 32; i < qq * 32 + 32; ++i)
    wmodb[(b * 128 + c) * 128 + i] = f2bf(Wmd[c * 128 + i] * q2[i] * rs);
}

// ---------- 3. q_t = wmod @ x  (bf16 MFMA GEMM, bf16 out) ------------------
__global__ __launch_bounds__(256) void k_qt_mfma(
    const unsigned short* __restrict__ wmodb,
    const unsigned short* __restrict__ xTb,
    unsigned short* __restrict__ q_tb) {
  int b = blockIdx.x;
  int n0 = blockIdx.y * 128;
  int t = threadIdx.x;
  int w = t >> 6, l = t & 63;
  int lr = l & 15, lg = l >> 4;

  __shared__ __align__(16) unsigned short Asw[128 * 128];
  __shared__ __align__(16) unsigned short Bsw[128 * 128];
  char* Ab = reinterpret_cast<char*>(Asw);
  char* Bb = reinterpret_cast<char*>(Bsw);

  const unsigned short* asrc = wmodb + (size_t)b * 128 * 128;
  const unsigned short* bsrc = xTb + ((size_t)(b & 3) * 4096 + n0) * 128;
#pragma unroll
  for (int it = 0; it < 8; ++it) {
    int idx = it * 256 + t;
    int row = idx >> 4, cb = (idx & 15) * 16;
    int dst = row * 256 + (cb ^ ((row & 7) << 4));
    *reinterpret_cast<u16x8*>(Ab + dst) = *reinterpret_cast<const u16x8*>(asrc + idx * 8);
    *reinterpret_cast<u16x8*>(Bb + dst) = *reinterpret_cast<const u16x8*>(bsrc + idx * 8);
  }
  __syncthreads();

  const f32x4 z4 = {0.f, 0.f, 0.f, 0.f};
  f32x4 acc[8][2];
#pragma unroll
  for (int mf = 0; mf < 8; ++mf) { acc[mf][0] = z4; acc[mf][1] = z4; }

#pragma unroll
  for (int ks = 0; ks < 4; ++ks) {
    int cb = ks * 64 + lg * 16;
    short8v bf[2];
#pragma unroll
    for (int nf = 0; nf < 2; ++nf) {
      int row = w * 32 + nf * 16 + lr;
      bf[nf] = *reinterpret_cast<const short8v*>(Bb + row * 256 + (cb ^ ((row & 7) << 4)));
    }
#pragma unroll
    for (int mf = 0; mf < 8; ++mf) {
      int row = mf * 16 + lr;
      short8v af = *reinterpret_cast<const short8v*>(Ab + row * 256 + (cb ^ ((row & 7) << 4)));
      acc[mf][0] = __builtin_amdgcn_mfma_f32_16x16x32_bf16(af, bf[0], acc[mf][0], 0, 0, 0);
      acc[mf][1] = __builtin_amdgcn_mfma_f32_16x16x32_bf16(af, bf[1], acc[mf][1], 0, 0, 0);
    }
  }

#pragma unroll
  for (int mf = 0; mf < 8; ++mf)
#pragma unroll
    for (int nf = 0; nf < 2; ++nf)
#pragma unroll
      for (int r = 0; r < 4; ++r) {
        int o = mf * 16 + lg * 4 + r;
        int px = n0 + w * 32 + nf * 16 + lr;
        q_tb[((size_t)(b * 128 + o)) * 4096 + px] = f2bf(acc[mf][nf][r]);
      }
}

// ---------- 4. depthwise 3x3 stride-2 conv (bf16 in, f32 out) --------------
__global__ void k_dwconv(const unsigned short* __restrict__ q_tb,
                         const float* __restrict__ dw_w,
                         const float* __restrict__ dw_b, float* __restrict__ t0) {
  int bid = blockIdx.x;  // 4096 = 8*128*4
  int t = threadIdx.x;
  int b = bid >> 9;
  int c = (bid >> 2) & 127;
  int px = (bid & 3) * 256 + t;  // 0..1023
  int i = px >> 5, j = px & 31;
  float w[9];
#pragma unroll
  for (int q = 0; q < 9; ++q) w[q] = dw_w[c * 9 + q];
  const unsigned short* src = q_tb + (size_t)(b * 128 + c) * 4096;
  float acc = dw_b[c];
#pragma unroll
  for (int dy = 0; dy < 3; ++dy) {
    int yy = 2 * i - 1 + dy;
    if (yy < 0 || yy > 63) continue;
#pragma unroll
    for (int dx = 0; dx < 3; ++dx) {
      int xx = 2 * j - 1 + dx;
      if (xx < 0 || xx > 63) continue;
      acc += w[dy * 3 + dx] * bf2f(src[yy * 64 + xx]);
    }
  }
  t0[(b * 128 + c) * 1024 + px] = acc;
}

// ---------- 5. LN + GELU + offset + grids (LDS-staged) ---------------------
__global__ __launch_bounds__(256) void k_ln_off(
    const float* __restrict__ t0, const float* __restrict__ ln_g,
    const float* __restrict__ ln_b, const float* __restrict__ off_w,
    float* __restrict__ posg, float* __restrict__ grid_out,
    float* __restrict__ ref_out) {
  int b = blockIdx.x;
  int s0 = blockIdx.y * 64;
  int t = threadIdx.x;
  __shared__ float tile[128][64];
  __shared__ float red0[4][64], red1[4][64];

  for (int p = 0; p < 32; ++p) {
    int idx = p * 256 + t;
    int c = idx >> 6, s = idx & 63;
    tile[c][s] = t0[(b * 128 + c) * 1024 + s0 + s];
  }
  __syncthreads();

  int s = t & 63, cg = t >> 6;
  float sum = 0.f, sq = 0.f;
  for (int cc = 0; cc < 32; ++cc) {
    float v = tile[cg * 32 + cc][s];
    sum += v; sq += v * v;
  }
  red0[cg][s] = sum; red1[cg][s] = sq;
  __syncthreads();
  float tsum = red0[0][s] + red0[1][s] + red0[2][s] + red0[3][s];
  float tsq  = red1[0][s] + red1[1][s] + red1[2][s] + red1[3][s];
  float mu = tsum * (1.0f / 128.0f);
  float var = tsq * (1.0f / 128.0f) - mu * mu;
  float rstd = 1.0f / sqrtf(var + 1e-5f);
  float o0 = 0.f, o1 = 0.f;
  for (int cc = 0; cc < 32; ++cc) {
    int c = cg * 32 + cc;
    float v = tile[c][s];
    float xn = (v - mu) * rstd * ln_g[c] + ln_b[c];
    float g = 0.5f * xn * (1.0f + erff(xn * 0.7071067811865476f));
    o0 += off_w[c] * g;
    o1 += off_w[128 + c] * g;
  }
  __syncthreads();
  red0[cg][s] = o0; red1[cg][s] = o1;
  __syncthreads();
  if (t < 64) {
    float off0 = red0[0][s] + red0[1][s] + red0[2][s] + red0[3][s];
    float off1 = red1[0][s] + red1[1][s] + red1[2][s] + red1[3][s];
    float offy = tanhf(off0) * (1.0f / 31.0f) * 2.0f;
    float offx = tanhf(off1) * (1.0f / 31.0f) * 2.0f;
    int sg = s0 + s;
    int i = sg >> 5, j = sg & 31;
    float ry = (0.5f + (float)i) / 31.0f * 2.0f - 1.0f;
    float rx = (0.5f + (float)j) / 31.0f * 2.0f - 1.0f;
    float posy = offy + ry;
    float posx = offx + rx;
    int bp = (b & 3) * 2 + (b >> 2);
    float2 g2; g2.x = posx; g2.y = posy;
    *reinterpret_cast<float2*>(&grid_out[(bp * 1024 + sg) * 2]) = g2;
    float2 r2; r2.x = ry; r2.y = rx;
    *reinterpret_cast<float2*>(&ref_out[(b * 1024 + sg) * 2]) = r2;
    float2 p2;
    p2.x = (posx + 1.0f) * 0.5f * 63.0f;
    p2.y = (posy + 1.0f) * 0.5f * 63.0f;
    *reinterpret_cast<float2*>(&posg[(b * 1024 + sg) * 2]) = p2;
  }
}

// ---------- 6. bilinear grid sample -> bf16 xs -----------------------------
__global__ void k_gsample(const float* __restrict__ y_t, const float* __restrict__ posg,
                          unsigned short* __restrict__ xsb) {
  int b = blockIdx.x;
  int s = blockIdx.y * 2 + (threadIdx.x >> 7);
  int c = threadIdx.x & 127;
  float gx = posg[(b * 1024 + s) * 2 + 0];
  float gy = posg[(b * 1024 + s) * 2 + 1];
  float x0 = floorf(gx), y0 = floorf(gy);
  float x1 = x0 + 1.0f, y1 = y0 + 1.0f;
  float wa = (x1 - gx) * (y1 - gy);
  float wb = (gx - x0) * (y1 - gy);
  float wc = (x1 - gx) * (gy - y0);
  float wd = (gx - x0) * (gy - y0);
  int n = b & 3;
  const float* base = y_t + n * 64 * 64 * 128 + c;
  float acc = 0.f;
  if (x0 >= 0.f && x0 <= 63.f && y0 >= 0.f && y0 <= 63.f)
    acc += wa * base[((int)y0 * 64 + (int)x0) * 128];
  if (x1 >= 0.f && x1 <= 63.f && y0 >= 0.f && y0 <= 63.f)
    acc += wb * base[((int)y0 * 64 + (int)x1) * 128];
  if (x0 >= 0.f && x0 <= 63.f && y1 >= 0.f && y1 <= 63.f)
    acc += wc * base[((int)y1 * 64 + (int)x0) * 128];
  if (x1 >= 0.f && x1 <= 63.f && y1 >= 0.f && y1 <= 63.f)
    acc += wd * base[((int)y1 * 64 + (int)x1) * 128];
  xsb[(b * 1024 + s) * 128 + c] = f2bf(acc);
}

// ---------- 7. K / V projections via MFMA (weights cast in staging) --------
__global__ __launch_bounds__(256) void k_projkv_mfma(
    const unsigned short* __restrict__ xsb, const float* __restrict__ Wk,
    const float* __restrict__ Wv, const float* __restrict__ bk,
    const float* __restrict__ bv, unsigned short* __restrict__ kb,
    unsigned short* __restrict__ vb) {
  int b = blockIdx.x, nt = blockIdx.y, z = blockIdx.z;
  int t = threadIdx.x;
  int w = t >> 6, l = t & 63;
  int lr = l & 15, lg = l >> 4;

  __shared__ __align__(16) unsigned short Asw[128 * 128];
  __shared__ __align__(16) unsigned short Bsw[128 * 128];
  char* Ab = reinterpret_cast<char*>(Asw);
  char* Bb = reinterpret_cast<char*>(Bsw);

  const float* asrcf = (z == 0) ? Wk : Wv;
  const unsigned short* bsrc = xsb + ((size_t)b * 1024 + nt * 128) * 128;
  const float* bias = (z == 0) ? bk : bv;
#pragma unroll
  for (int it = 0; it < 8; ++it) {
    int idx = it * 256 + t;
    int row = idx >> 4, cb = (idx & 15) * 16;
    int dst = row * 256 + (cb ^ ((row & 7) << 4));
    float4 f0 = *reinterpret_cast<const float4*>(asrcf + idx * 8);
    float4 f1 = *reinterpret_cast<const float4*>(asrcf + idx * 8 + 4);
    u16x8 av;
    av[0] = f2bf(f0.x); av[1] = f2bf(f0.y); av[2] = f2bf(f0.z); av[3] = f2bf(f0.w);
    av[4] = f2bf(f1.x); av[5] = f2bf(f1.y); av[6] = f2bf(f1.z); av[7] = f2bf(f1.w);
    *reinterpret_cast<u16x8*>(Ab + dst) = av;
    *reinterpret_cast<u16x8*>(Bb + dst) = *reinterpret_cast<const u16x8*>(bsrc + idx * 8);
  }
  __syncthreads();

  const f32x4 z4 = {0.f, 0.f, 0.f, 0.f};
  f32x4 acc[8][2];
#pragma unroll
  for (int mf = 0; mf < 8; ++mf) { acc[mf][0] = z4; acc[mf][1] = z4; }

#pragma unroll
  for (int ks = 0; ks < 4; ++ks) {
    int cb = ks * 64 + lg * 16;
    short8v bf[2];
#pragma unroll
    for (int nf = 0; nf < 2; ++nf) {
      int row = w * 32 + nf * 16 + lr;
      bf[nf] = *reinterpret_cast<const short8v*>(Bb + row * 256 + (cb ^ ((row & 7) << 4)));
    }
#pragma unroll
    for (int mf = 0; mf < 8; ++mf) {
      int row = mf * 16 + lr;
      short8v af = *reinterpret_cast<const short8v*>(Ab + row * 256 + (cb ^ ((row & 7) << 4)));
      acc[mf][0] = __builtin_amdgcn_mfma_f32_16x16x32_bf16(af, bf[0], acc[mf][0], 0, 0, 0);
      acc[mf][1] = __builtin_amdgcn_mfma_f32_16x16x32_bf16(af, bf[1], acc[mf][1], 0, 0, 0);
    }
  }

  if (z == 0) {
#pragma unroll
    for (int mf = 0; mf < 8; ++mf) {
      int o0 = mf * 16 + lg * 4;
      int h = o0 >> 5, d0 = o0 & 31;
#pragma unroll
      for (int nf = 0; nf < 2; ++nf) {
        int n = nt * 128 + w * 32 + nf * 16 + lr;
        u16x4 pk;
#pragma unroll
        for (int r = 0; r < 4; ++r) pk[r] = f2bf(acc[mf][nf][r] + bias[o0 + r]);
        *reinterpret_cast<u16x4*>(kb + ((size_t)(b * 4 + h) * 1024 + n) * 32 + d0) = pk;
      }
    }
  } else {
#pragma unroll
    for (int mf = 0; mf < 8; ++mf)
#pragma unroll
      for (int nf = 0; nf < 2; ++nf)
#pragma unroll
        for (int r = 0; r < 4; ++r) {
          int o = mf * 16 + lg * 4 + r;
          int n = nt * 128 + w * 32 + nf * 16 + lr;
          vb[(size_t)(b * 128 + o) * 1024 + n] = f2bf(acc[mf][nf][r] + bias[o]);
        }
  }
}

// ---------- 8. attention: dbuf K/V, 1 barrier/tile, swizzled P -------------
__global__ __launch_bounds__(256) void k_attn_mfma(
    const float* __restrict__ q_, const unsigned short* __restrict__ kb,
    const unsigned short* __restrict__ vb, unsigned short* __restrict__ obmcb) {
  int bh = blockIdx.x;          // 32
  int b = bh >> 2, h = bh & 3;
  int m0 = blockIdx.y * 128;    // 16 tiles
  int t = threadIdx.x;
  int w = t >> 6, l = t & 63;
  int lr = l & 15, lg = l >> 4;

  __shared__ __align__(16) unsigned short K_lds[2][2048];
  __shared__ __align__(16) unsigned short V_lds[2][2048];
  __shared__ __align__(16) unsigned short P_lds[8192];

  short8v qa[2];
#pragma unroll
  for (int mf = 0; mf < 2; ++mf) {
    int m = m0 + w * 32 + mf * 16 + lr;
    const float* qp = q_ + ((size_t)(b * 2048 + m)) * 128 + h * 32 + lg * 8;
    float4 x0 = *reinterpret_cast<const float4*>(qp);
    float4 x1 = *reinterpret_cast<const float4*>(qp + 4);
    float vals[8] = {x0.x, x0.y, x0.z, x0.w, x1.x, x1.y, x1.z, x1.w};
    short8v q8;
#pragma unroll
    for (int j = 0; j < 8; ++j) q8[j] = (short)f2bf(vals[j] * SCALE_F);
    qa[mf] = q8;
  }

  const unsigned short* kbase = kb + (size_t)bh * 1024 * 32;
  const unsigned short* vbase = vb + (size_t)bh * 32 * 1024;
  int ksl_n = t & 63, ksl_d = t >> 6;
  int vsl_d = t & 31, vsl_nb = t >> 5;

  u16x8 kreg = *reinterpret_cast<const u16x8*>(kbase + ((size_t)ksl_n) * 32 + ksl_d * 8);
  u16x8 vreg = *reinterpret_cast<const u16x8*>(vbase + (size_t)vsl_d * 1024 + vsl_nb * 8);
  *reinterpret_cast<u16x8*>(&K_lds[0][t * 8]) = kreg;
  *reinterpret_cast<u16x8*>(&V_lds[0][t * 8]) = vreg;
  __syncthreads();

  const f32x4 z4 = {0.f, 0.f, 0.f, 0.f};
  f32x4 oacc[2][2];
  float lsum[2][4];
#pragma unroll
  for (int mf = 0; mf < 2; ++mf) {
#pragma unroll
    for (int df = 0; df < 2; ++df) oacc[mf][df] = z4;
#pragma unroll
    for (int r = 0; r < 4; ++r) lsum[mf][r] = 0.f;
  }

  int swzW = ((lr >> 3) & 1) << 3;
  int swzR = (lg & 1) << 3;
  int cur = 0;
  for (int nt = 0; nt < 16; ++nt) {
    if (nt < 15) {
      kreg = *reinterpret_cast<const u16x8*>(
          kbase + ((size_t)((nt + 1) * 64 + ksl_n)) * 32 + ksl_d * 8);
      vreg = *reinterpret_cast<const u16x8*>(
          vbase + (size_t)vsl_d * 1024 + (nt + 1) * 64 + vsl_nb * 8);
    }

    short8v kfr[4];
#pragma unroll
    for (int nf = 0; nf < 4; ++nf)
      kfr[nf] = *reinterpret_cast<const short8v*>(&K_lds[cur][(lg * 64 + nf * 16 + lr) * 8]);
    f32x4 s[2][4];
#pragma unroll
    for (int mf = 0; mf < 2; ++mf)
#pragma unroll
      for (int nf = 0; nf < 4; ++nf)
        s[mf][nf] = __builtin_amdgcn_mfma_f32_16x16x32_bf16(qa[mf], kfr[nf], z4, 0, 0, 0);

#pragma unroll
    for (int mf = 0; mf < 2; ++mf) {
#pragma unroll
      for (int nf = 0; nf < 4; ++nf) {
        int sbase = (w * 256 + (nf * 2 + (lr >> 3)) * 32 + mf * 16 + lg * 4) * 8 + (lr & 7);
#pragma unroll
        for (int r = 0; r < 4; ++r) {
          float pe = __expf(s[mf][nf][r]);
          lsum[mf][r] += pe;
          P_lds[(sbase + r * 8) ^ swzW] = f2bf(pe);
        }
      }
    }

#pragma unroll
    for (int ks = 0; ks < 2; ++ks) {
      short8v pa[2], vf[2];
#pragma unroll
      for (int mf = 0; mf < 2; ++mf)
        pa[mf] = *reinterpret_cast<const short8v*>(
            &P_lds[((w * 256 + (ks * 4 + lg) * 32 + mf * 16 + lr) * 8) ^ swzR]);
#pragma unroll
      for (int df = 0; df < 2; ++df)
        vf[df] = *reinterpret_cast<const short8v*>(
            &V_lds[cur][((ks * 4 + lg) * 32 + df * 16 + lr) * 8]);
#pragma unroll
      for (int mf = 0; mf < 2; ++mf)
#pragma unroll
        for (int df = 0; df < 2; ++df)
          oacc[mf][df] = __builtin_amdgcn_mfma_f32_16x16x32_bf16(pa[mf], vf[df], oacc[mf][df], 0, 0, 0);
    }

    if (nt < 15) {
      *reinterpret_cast<u16x8*>(&K_lds[cur ^ 1][t * 8]) = kreg;
      *reinterpret_cast<u16x8*>(&V_lds[cur ^ 1][t * 8]) = vreg;
      __syncthreads();
      cur ^= 1;
    }
  }

#pragma unroll
  for (int mf = 0; mf < 2; ++mf) {
#pragma unroll
    for (int r = 0; r < 4; ++r) {
      float v = lsum[mf][r];
      v += __shfl_xor(v, 1); v += __shfl_xor(v, 2);
      v += __shfl_xor(v, 4); v += __shfl_xor(v, 8);
      float inv = 1.0f / v;
      int m = m0 + w * 32 + mf * 16 + lg * 4 + r;
      unsigned short* op = obmcb + ((size_t)(b * 2048 + m)) * 128 + h * 32;
      op[lr] = f2bf(oacc[mf][0][r] * inv);
      op[16 + lr] = f2bf(oacc[mf][1][r] * inv);
    }
  }
}

// ---------- 9. output projection via MFMA ----------------------------------
__global__ __launch_bounds__(256) void k_out_mfma(
    const unsigned short* __restrict__ obmcb, const float* __restrict__ Wo,
    const float* __restrict__ bo, float* __restrict__ yo) {
  int b = blockIdx.x, mt = blockIdx.y;
  int t = threadIdx.x;
  int w = t >> 6, l = t & 63;
  int lr = l & 15, lg = l >> 4;

  __shared__ __align__(16) unsigned short Asw[128 * 128];
  __shared__ __align__(16) unsigned short Bsw[128 * 128];
  char* Ab = reinterpret_cast<char*>(Asw);
  char* Bb = reinterpret_cast<char*>(Bsw);

  const unsigned short* bsrc = obmcb + ((size_t)b * 2048 + mt * 128) * 128;
#pragma unroll
  for (int it = 0; it < 8; ++it) {
    int idx = it * 256 + t;
    int row = idx >> 4, cb = (idx & 15) * 16;
    int dst = row * 256 + (cb ^ ((row & 7) << 4));
    float4 f0 = *reinterpret_cast<const float4*>(Wo + idx * 8);
    float4 f1 = *reinterpret_cast<const float4*>(Wo + idx * 8 + 4);
    u16x8 av;
    av[0] = f2bf(f0.x); av[1] = f2bf(f0.y); av[2] = f2bf(f0.z); av[3] = f2bf(f0.w);
    av[4] = f2bf(f1.x); av[5] = f2bf(f1.y); av[6] = f2bf(f1.z); av[7] = f2bf(f1.w);
    *reinterpret_cast<u16x8*>(Ab + dst) = av;
    *reinterpret_cast<u16x8*>(Bb + dst) = *reinterpret_cast<const u16x8*>(bsrc + idx * 8);
  }
  __syncthreads();

  const f32x4 z4 = {0.f, 0.f, 0.f, 0.f};
  f32x4 acc[8][2];
#pragma unroll
  for (int mf = 0; mf < 8; ++mf) { acc[mf][0] = z4; acc[mf][1] = z4; }

#pragma unroll
  for (int ks = 0; ks < 4; ++ks) {
    int cb = ks * 64 + lg * 16;
    short8v bf[2];
#pragma unroll
    for (int nf = 0; nf < 2; ++nf) {
      int row = w * 32 + nf * 16 + lr;
      bf[nf] = *reinterpret_cast<const short8v*>(Bb + row * 256 + (cb ^ ((row & 7) << 4)));
    }
#pragma unroll
    for (int mf = 0; mf < 8; ++mf) {
      int row = mf * 16 + lr;
      short8v af = *reinterpret_cast<const short8v*>(Ab + row * 256 + (cb ^ ((row & 7) << 4)));
      acc[mf][0] = __builtin_amdgcn_mfma_f32_16x16x32_bf16(af, bf[0], acc[mf][0], 0, 0, 0);
      acc[mf][1] = __builtin_amdgcn_mfma_f32_16x16x32_bf16(af, bf[1], acc[mf][1], 0, 0, 0);
    }
  }

#pragma unroll
  for (int mf = 0; mf < 8; ++mf) {
    int o0 = mf * 16 + lg * 4;
#pragma unroll
    for (int nf = 0; nf < 2; ++nf) {
      int m = mt * 128 + w * 32 + nf * 16 + lr;
      float4 rv;
      rv.x = acc[mf][nf][0] + bo[o0 + 0];
      rv.y = acc[mf][nf][1] + bo[o0 + 1];
      rv.z = acc[mf][nf][2] + bo[o0 + 2];
      rv.w = acc[mf][nf][3] + bo[o0 + 3];
      *reinterpret_cast<float4*>(&yo[((size_t)(b * 2048 + m)) * 128 + o0]) = rv;
    }
  }
}

// ============================================================================
extern "C" void kernel_launch(void* const* d_in, const int* in_sizes, int n_in,
                              void* d_out, int out_size, void* d_ws, size_t ws_size,
                              hipStream_t stream) {
  const float* x     = (const float*)d_in[0];
  const float* y     = (const float*)d_in[1];
  const float* q_    = (const float*)d_in[2];
  const float* mask_ = (const float*)d_in[3];
  const float* Wq    = (const float*)d_in[4];
  const float* bq    = (const float*)d_in[5];
  const float* Wmd   = (const float*)d_in[6];
  const float* dw_w  = (const float*)d_in[7];
  const float* dw_b  = (const float*)d_in[8];
  const float* ln_g  = (const float*)d_in[9];
  const float* ln_b  = (const float*)d_in[10];
  const float* off_w = (const float*)d_in[11];
  const float* Wk    = (const float*)d_in[12];
  const float* bk    = (const float*)d_in[13];
  const float* Wv    = (const float*)d_in[14];
  const float* bv    = (const float*)d_in[15];
  const float* Wo    = (const float*)d_in[16];
  const float* bo    = (const float*)d_in[17];

  float* out = (float*)d_out;
  float* yo       = out;            // 8*2048*128
  float* grid_out = out + 2097152;  // 16384
  float* ref_out  = grid_out + 16384;

  float* ws    = (float*)d_ws;
  float* y_t   = ws;                // 2097152 f32
  float* qpart = y_t + 2097152;     // 65536 f32
  float* mpart = qpart + 65536;     // 512 f32
  float* t0    = mpart + 512;       // 1048576 f32
  float* posg  = t0 + 1048576;      // 16384 f32
  unsigned short* kbb   = (unsigned short*)(posg + 16384);  // 1048576 u16
  unsigned short* vbb   = kbb + 1048576;                    // 1048576 u16
  unsigned short* xTb   = vbb + 1048576;                    // 2097152 u16
  unsigned short* wmodb = xTb + 2097152;                    // 131072 u16
  unsigned short* xsb   = wmodb + 131072;                   // 1048576 u16
  unsigned short* obmcb = xsb + 1048576;                    // 2097152 u16
  unsigned short* q_tb  = obmcb + 2097152;                  // 4194304 u16

  hipLaunchKernelGGL(k_stage1, dim3(768), dim3(256), 0, stream,
                     y, x, q_, mask_, y_t, xTb, qpart, mpart);
  hipLaunchKernelGGL(k_wmod, dim3(8), dim3(512), 0, stream,
                     qpart, mpart, Wq, bq, Wmd, wmodb);
  hipLaunchKernelGGL(k_qt_mfma, dim3(8, 32), dim3(256), 0, stream, wmodb, xTb, q_tb);
  hipLaunchKernelGGL(k_dwconv, dim3(4096), dim3(256), 0, stream, q_tb, dw_w, dw_b, t0);
  hipLaunchKernelGGL(k_ln_off, dim3(8, 16), dim3(256), 0, stream,
                     t0, ln_g, ln_b, off_w, posg, grid_out, ref_out);
  hipLaunchKernelGGL(k_gsample, dim3(8, 512), dim3(256), 0, stream, y_t, posg, xsb);
  hipLaunchKernelGGL(k_projkv_mfma, dim3(8, 8, 2), dim3(256), 0, stream,
                     xsb, Wk, Wv, bk, bv, kbb, vbb);
  hipLaunchKernelGGL(k_attn_mfma, dim3(32, 16), dim3(256), 0, stream, q_, kbb, vbb, obmcb);
  hipLaunchKernelGGL(k_out_mfma, dim3(8, 16), dim3(256), 0, stream, obmcb, Wo, bo, yo);
}